// Round 1
// baseline (114.280 us; speedup 1.0000x reference)
//
#include <hip/hip_runtime.h>

// ---------------------------------------------------------------------------
// BatchRelationalModule: b=16, c=64, L=256, F=64
// Factorization: layer0 pre-act = A[b,q,f] + B'[b,p,f]  (B' has bg0 folded in)
//   A[b,l,f]  = sum_{d<65} feats[b,l,d] * Wg0[f,d]        (feats d=64 is coord l)
//   B'[b,l,f] = sum_{d<65} feats[b,l,d] * Wg0[f,65+d] + bg0[f]
// Then per pair: X = relu(A_q + B'_p); Y1 = relu(X@Wg1^T + bg1);
//                Y2 = relu(Y1@Wg2^T + bg2); S[b] = sum_{p,q} Y2
// Finally: out = relu(S@Wp^T + bp) @ Wo^T + bo
// ---------------------------------------------------------------------------

typedef short s8v __attribute__((ext_vector_type(8)));   // 8 x bf16 (raw bits)
typedef float f4v __attribute__((ext_vector_type(4)));   // MFMA accumulator

#define LDA 68   // padded fp32 row for A-tile in LDS (272 B: 16B-aligned, 2-way banks)
#define LDY 72   // padded bf16 row for Y1 scratch (144 B: 16B-aligned)

__device__ __forceinline__ short bfr(float v) {
  return __builtin_bit_cast(short, (__bf16)v);           // fp32 -> bf16 (RNE)
}

// ---------------------------------------------------------------------------
// Kernel 1: precompute A and B' (fp32), also zero the S accumulator.
// grid: 256 blocks (16 b x 16 l-tiles of 16), 256 threads.
// ---------------------------------------------------------------------------
__global__ __launch_bounds__(256) void k_pre(
    const float* __restrict__ x, const float* __restrict__ Wg0,
    const float* __restrict__ bg0, float* __restrict__ Ag,
    float* __restrict__ Bg, float* __restrict__ Sg) {
  __shared__ float ws[64 * 131];   // Wg0 rows, stride 131 (odd-ish -> 2-way banks)
  __shared__ float xs[64 * 17];    // x[ch][l] slice, stride 17

  const int t = threadIdx.x;
  const int b = blockIdx.x >> 4;
  const int l0 = (blockIdx.x & 15) * 16;

  if (blockIdx.x == 0) {           // zero S (d_ws is poisoned 0xAA each launch)
    for (int i = t; i < 16 * 64; i += 256) Sg[i] = 0.f;
  }
  for (int i = t; i < 64 * 130; i += 256) {
    int f = i / 130, d = i - f * 130;
    ws[f * 131 + d] = Wg0[i];
  }
  for (int i = t; i < 64 * 16; i += 256) {
    int ch = i >> 4, li = i & 15;
    xs[ch * 17 + li] = x[b * 16384 + ch * 256 + l0 + li];
  }
  __syncthreads();

  const int f = t & 63;
  const int w = t >> 6;            // wave id -> li base
  float accA[4] = {0.f, 0.f, 0.f, 0.f};
  float accB[4] = {0.f, 0.f, 0.f, 0.f};
  for (int d = 0; d < 64; ++d) {
    float wa = ws[f * 131 + d];
    float wb = ws[f * 131 + 65 + d];
#pragma unroll
    for (int i = 0; i < 4; ++i) {
      float xv = xs[d * 17 + w + 4 * i];   // broadcast across lanes
      accA[i] += xv * wa;
      accB[i] += xv * wb;
    }
  }
  const float wca = ws[f * 131 + 64];      // coord weight (A half)
  const float wcb = ws[f * 131 + 129];     // coord weight (B half)
  const float bias = bg0[f];
#pragma unroll
  for (int i = 0; i < 4; ++i) {
    int l = l0 + w + 4 * i;
    Ag[(b * 256 + l) * 64 + f] = accA[i] + (float)l * wca;
    Bg[(b * 256 + l) * 64 + f] = accB[i] + (float)l * wcb + bias;
  }
}

// ---------------------------------------------------------------------------
// Kernel 2: the heavy pair loop. grid (32 pgroups, 16 b) x 256 threads.
// Block: stage A[b] (fp32) in LDS; each wave owns 64 q-rows; loop 8 p values.
// Per (p, qtile): X=relu(A+B') built in MFMA A-layout -> layer1 MFMA (weights
// in registers, bias in C) -> relu -> per-wave LDS scratch -> layer2 MFMA ->
// relu -> column-sum accumulators. LDS = 69632+9216+256 = 79104 B -> 2 blk/CU.
// ---------------------------------------------------------------------------
__global__ __launch_bounds__(256, 2) void k_main(
    const float* __restrict__ Ag, const float* __restrict__ Bg,
    const float* __restrict__ Wg1, const float* __restrict__ bg1,
    const float* __restrict__ Wg2, const float* __restrict__ bg2,
    float* __restrict__ Sg) {
  __shared__ __align__(16) float As[256 * LDA];
  __shared__ __align__(16) short Y1s[4][16 * LDY];
  __shared__ float Sblk[64];

  const int t = threadIdx.x;
  const int wid = t >> 6;
  const int lane = t & 63;
  const int mm = lane & 15;        // MFMA "lane&15" index
  const int quad = lane >> 4;
  const int b = blockIdx.y;
  const int p0 = blockIdx.x * 8;

  if (t < 64) Sblk[t] = 0.f;

  // ---- stage A[b] (16384 fp32) into LDS, padded rows ----
  const float4* Ab4 = (const float4*)(Ag + b * 16384);
  for (int i = 0; i < 16; ++i) {
    int flat4 = t + 256 * i;                 // float4 index
    int q = flat4 >> 4, c4 = flat4 & 15;
    float4 v = Ab4[flat4];
    *(float4*)&As[q * LDA + c4 * 4] = v;
  }

  // ---- weight fragments in registers (B-operand layout: row g=lane&15,
  //      8 contiguous k) + per-lane biases ----
  s8v W1f[4][2], W2f[4][2];
  float bg1v[4], bg2v[4];
#pragma unroll
  for (int gt = 0; gt < 4; ++gt) {
    bg1v[gt] = bg1[gt * 16 + mm];
    bg2v[gt] = bg2[gt * 16 + mm];
#pragma unroll
    for (int kh = 0; kh < 2; ++kh) {
      const float* r1 = Wg1 + (gt * 16 + mm) * 64 + kh * 32 + quad * 8;
      const float* r2 = Wg2 + (gt * 16 + mm) * 64 + kh * 32 + quad * 8;
      s8v w1, w2;
#pragma unroll
      for (int j = 0; j < 8; ++j) { w1[j] = bfr(r1[j]); w2[j] = bfr(r2[j]); }
      W1f[gt][kh] = w1;
      W2f[gt][kh] = w2;
    }
  }
  __syncthreads();

  float cs[4] = {0.f, 0.f, 0.f, 0.f};       // col-sums (col = gt*16+mm)
  short* Y1w = Y1s[wid];
  const float* Bb = Bg + (b * 256 + p0) * 64;

  // prefetch B' for first p: 16 fp32 per lane (k positions of both k-halves)
  const float4* Bp4 = (const float4*)Bb;
  float4 bq0 = Bp4[quad * 2],     bq1 = Bp4[quad * 2 + 1];
  float4 bq2 = Bp4[8 + quad * 2], bq3 = Bp4[9 + quad * 2];

  for (int ip = 0; ip < 8; ++ip) {
    const int pn = (ip < 7) ? ip + 1 : 7;   // next-p prefetch (clamped)
    const float4* Bn4 = (const float4*)(Bb + pn * 64);
    float4 bn0 = Bn4[quad * 2],     bn1 = Bn4[quad * 2 + 1];
    float4 bn2 = Bn4[8 + quad * 2], bn3 = Bn4[9 + quad * 2];

#pragma unroll
    for (int qt = 0; qt < 4; ++qt) {
      const float* arow = &As[(wid * 64 + qt * 16 + mm) * LDA];
      // X fragments in A-operand layout: k = kh*32 + quad*8 + j
      float4 a0 = *(const float4*)(arow + quad * 8);
      float4 a1 = *(const float4*)(arow + quad * 8 + 4);
      float4 a2 = *(const float4*)(arow + 32 + quad * 8);
      float4 a3 = *(const float4*)(arow + 36 + quad * 8);
      s8v x0, x1;
      x0[0] = bfr(fmaxf(a0.x + bq0.x, 0.f));
      x0[1] = bfr(fmaxf(a0.y + bq0.y, 0.f));
      x0[2] = bfr(fmaxf(a0.z + bq0.z, 0.f));
      x0[3] = bfr(fmaxf(a0.w + bq0.w, 0.f));
      x0[4] = bfr(fmaxf(a1.x + bq1.x, 0.f));
      x0[5] = bfr(fmaxf(a1.y + bq1.y, 0.f));
      x0[6] = bfr(fmaxf(a1.z + bq1.z, 0.f));
      x0[7] = bfr(fmaxf(a1.w + bq1.w, 0.f));
      x1[0] = bfr(fmaxf(a2.x + bq2.x, 0.f));
      x1[1] = bfr(fmaxf(a2.y + bq2.y, 0.f));
      x1[2] = bfr(fmaxf(a2.z + bq2.z, 0.f));
      x1[3] = bfr(fmaxf(a2.w + bq2.w, 0.f));
      x1[4] = bfr(fmaxf(a3.x + bq3.x, 0.f));
      x1[5] = bfr(fmaxf(a3.y + bq3.y, 0.f));
      x1[6] = bfr(fmaxf(a3.z + bq3.z, 0.f));
      x1[7] = bfr(fmaxf(a3.w + bq3.w, 0.f));

      // ---- layer 1: bias preloaded into C operand ----
      f4v acc1[4];
#pragma unroll
      for (int gt = 0; gt < 4; ++gt) {
        f4v c = {bg1v[gt], bg1v[gt], bg1v[gt], bg1v[gt]};
        c = __builtin_amdgcn_mfma_f32_16x16x32_bf16(x0, W1f[gt][0], c, 0, 0, 0);
        c = __builtin_amdgcn_mfma_f32_16x16x32_bf16(x1, W1f[gt][1], c, 0, 0, 0);
        acc1[gt] = c;
      }
      // relu -> bf16 -> per-wave scratch (C/D layout: row=quad*4+r, col)
#pragma unroll
      for (int gt = 0; gt < 4; ++gt) {
#pragma unroll
        for (int r = 0; r < 4; ++r)
          Y1w[(quad * 4 + r) * LDY + gt * 16 + mm] = bfr(fmaxf(acc1[gt][r], 0.f));
      }
      // ---- layer 2: read Y1 back in A-operand layout ----
      s8v y0 = *(const s8v*)(Y1w + mm * LDY + quad * 8);
      s8v y1 = *(const s8v*)(Y1w + mm * LDY + 32 + quad * 8);
#pragma unroll
      for (int gt = 0; gt < 4; ++gt) {
        f4v c = {bg2v[gt], bg2v[gt], bg2v[gt], bg2v[gt]};
        c = __builtin_amdgcn_mfma_f32_16x16x32_bf16(y0, W2f[gt][0], c, 0, 0, 0);
        c = __builtin_amdgcn_mfma_f32_16x16x32_bf16(y1, W2f[gt][1], c, 0, 0, 0);
        cs[gt] += fmaxf(c[0], 0.f) + fmaxf(c[1], 0.f) +
                  fmaxf(c[2], 0.f) + fmaxf(c[3], 0.f);
      }
    }
    bq0 = bn0; bq1 = bn1; bq2 = bn2; bq3 = bn3;
  }

  // ---- reduce: cross-quad (lanes L, L+16, L+32, L+48 share a column) ----
#pragma unroll
  for (int gt = 0; gt < 4; ++gt) {
    float v = cs[gt];
    v += __shfl_xor(v, 16);
    v += __shfl_xor(v, 32);
    if (lane < 16) atomicAdd(&Sblk[gt * 16 + lane], v);
  }
  __syncthreads();
  if (t < 64) atomicAdd(&Sg[b * 64 + t], Sblk[t]);
}

// ---------------------------------------------------------------------------
// Kernel 3: f-network epilogue. grid 16 x 64 threads.
// ---------------------------------------------------------------------------
__global__ __launch_bounds__(64) void k_final(
    const float* __restrict__ S, const float* __restrict__ Wp,
    const float* __restrict__ bp, const float* __restrict__ Wo,
    const float* __restrict__ bo, float* __restrict__ out) {
  __shared__ float sv[64], tv[64];
  const int b = blockIdx.x, t = threadIdx.x;
  sv[t] = S[b * 64 + t];
  __syncthreads();
  float acc = bp[t];
  for (int g = 0; g < 64; ++g) acc += sv[g] * Wp[t * 64 + g];
  tv[t] = fmaxf(acc, 0.f);
  __syncthreads();
  float o = bo[t];
  for (int f = 0; f < 64; ++f) o += tv[f] * Wo[t * 64 + f];
  out[b * 64 + t] = o;
}

// ---------------------------------------------------------------------------
extern "C" void kernel_launch(void* const* d_in, const int* in_sizes, int n_in,
                              void* d_out, int out_size, void* d_ws, size_t ws_size,
                              hipStream_t stream) {
  const float* x   = (const float*)d_in[0];
  const float* Wg0 = (const float*)d_in[1];
  const float* bg0 = (const float*)d_in[2];
  const float* Wg1 = (const float*)d_in[3];
  const float* bg1 = (const float*)d_in[4];
  const float* Wg2 = (const float*)d_in[5];
  const float* bg2 = (const float*)d_in[6];
  const float* Wp  = (const float*)d_in[7];
  const float* bp  = (const float*)d_in[8];
  const float* Wo  = (const float*)d_in[9];
  const float* bo  = (const float*)d_in[10];
  float* out = (float*)d_out;

  float* Ag = (float*)d_ws;            // [16][256][64] fp32 = 1 MB
  float* Bg = Ag + 16 * 256 * 64;      // [16][256][64] fp32 = 1 MB
  float* Sg = Bg + 16 * 256 * 64;      // [16][64] fp32 accumulator

  k_pre<<<256, 256, 0, stream>>>(x, Wg0, bg0, Ag, Bg, Sg);
  k_main<<<dim3(32, 16), 256, 0, stream>>>(Ag, Bg, Wg1, bg1, Wg2, bg2, Sg);
  k_final<<<16, 64, 0, stream>>>(Sg, Wp, bp, Wo, bo, out);
}